// Round 2
// baseline (1807.440 us; speedup 1.0000x reference)
//
#include <hip/hip_runtime.h>
#include <stdint.h>

// Problem constants
#define M_ROWS 8192    // B*S = 4*2048
#define N_OUT  11008
#define K_IN   4096
#define RANK   192

typedef __attribute__((ext_vector_type(8))) short bf16x8;   // 8 bf16 = 4 VGPRs
typedef __attribute__((ext_vector_type(4))) float f32x4;

// async global->LDS, 16B per lane. LDS dst = wave-uniform base + lane*16.
#define GLDS16(g, l) __builtin_amdgcn_global_load_lds( \
    (const __attribute__((address_space(1))) unsigned int*)(g), \
    (__attribute__((address_space(3))) unsigned int*)(l), 16, 0, 0)

#define STR_IMPL(x) #x
#define VMW(n) asm volatile("s_waitcnt vmcnt(" STR_IMPL(n) ")" ::: "memory")
#define LKW(n) asm volatile("s_waitcnt lgkmcnt(" STR_IMPL(n) ")" ::: "memory")

// RTNE float -> bf16 bits (matches __float2bfloat16 for finite values)
static __device__ __forceinline__ unsigned short f2bf(float f) {
    union { float f; unsigned int u; } a; a.f = f;
    unsigned int u = a.u;
    u += 0x7fffu + ((u >> 16) & 1u);
    return (unsigned short)(u >> 16);
}

// ---------------------------------------------------------------------------
// Pass 1: wq = weight + Bd @ Bu  (f32), plus per-(row, colblock) min/max.
// Tile: 64 rows x 256 cols, K=192. 256 thr = 32(tx) x 8(ty); thread owns
// 8 rows x 8 CONSECUTIVE cols -> all LDS/global reads are float4 (b128).
// Bu read directly from global (3 MB, L2-resident; no buS staging/barriers).
// Per-element FMA order over k unchanged -> bit-identical to previous pass.
// grid (11008/64=172, 4096/256=16)
// ---------------------------------------------------------------------------
__global__ __launch_bounds__(256) void k_delta_minmax(
    const float* __restrict__ Wg, const float* __restrict__ Bd,
    const float* __restrict__ Bu, float* __restrict__ wq,
    float* __restrict__ pmin, float* __restrict__ pmax)
{
    __shared__ float bdT[RANK][68];   // transposed Bd tile (row stride 272B, 16B-aligned)
    const int t  = threadIdx.x;
    const int tx = t & 31, ty = t >> 5;
    const int row0 = blockIdx.x * 64;
    const int col0 = blockIdx.y * 256;

    for (int i = t; i < 64 * RANK; i += 256) {
        int r = i / RANK, k = i - r * RANK;
        bdT[k][r] = Bd[(size_t)(row0 + r) * RANK + k];
    }
    __syncthreads();

    float acc[8][8];
#pragma unroll
    for (int a = 0; a < 8; ++a)
#pragma unroll
        for (int b = 0; b < 8; ++b) acc[a][b] = 0.0f;

    const float* bup = Bu + col0 + tx * 8;
#pragma unroll 2
    for (int k = 0; k < RANK; ++k) {
        const float4 b0 = *(const float4*)(bup);
        const float4 b1 = *(const float4*)(bup + 4);
        bup += K_IN;
        const float4 d0 = *(const float4*)&bdT[k][ty * 8];
        const float4 d1 = *(const float4*)&bdT[k][ty * 8 + 4];
        const float bd[8] = {d0.x, d0.y, d0.z, d0.w, d1.x, d1.y, d1.z, d1.w};
        const float bv[8] = {b0.x, b0.y, b0.z, b0.w, b1.x, b1.y, b1.z, b1.w};
#pragma unroll
        for (int rr = 0; rr < 8; ++rr)
#pragma unroll
            for (int cc = 0; cc < 8; ++cc)
                acc[rr][cc] = fmaf(bd[rr], bv[cc], acc[rr][cc]);
    }

    float rmin[8], rmax[8];
#pragma unroll
    for (int rr = 0; rr < 8; ++rr) { rmin[rr] = 3.0e38f; rmax[rr] = -3.0e38f; }
#pragma unroll
    for (int rr = 0; rr < 8; ++rr) {
        const size_t gr = (size_t)(row0 + ty * 8 + rr);
        const float* wrow = Wg + gr * K_IN + col0 + tx * 8;
        const float4 w0 = *(const float4*)(wrow);
        const float4 w1 = *(const float4*)(wrow + 4);
        const float wv[8] = {w0.x, w0.y, w0.z, w0.w, w1.x, w1.y, w1.z, w1.w};
        float o[8];
#pragma unroll
        for (int cc = 0; cc < 8; ++cc) {
            float w = wv[cc] + acc[rr][cc];
            o[cc] = w;
            rmin[rr] = fminf(rmin[rr], w);
            rmax[rr] = fmaxf(rmax[rr], w);
        }
        float* orow = wq + gr * K_IN + col0 + tx * 8;
        *(float4*)(orow)     = make_float4(o[0], o[1], o[2], o[3]);
        *(float4*)(orow + 4) = make_float4(o[4], o[5], o[6], o[7]);
    }
#pragma unroll
    for (int off = 16; off >= 1; off >>= 1) {
#pragma unroll
        for (int rr = 0; rr < 8; ++rr) {
            rmin[rr] = fminf(rmin[rr], __shfl_xor(rmin[rr], off, 64));
            rmax[rr] = fmaxf(rmax[rr], __shfl_xor(rmax[rr], off, 64));
        }
    }
    if (tx == 0) {
#pragma unroll
        for (int rr = 0; rr < 8; ++rr) {
            int gr = row0 + ty * 8 + rr;
            pmin[(size_t)gr * 16 + blockIdx.y] = rmin[rr];
            pmax[(size_t)gr * 16 + blockIdx.y] = rmax[rr];
        }
    }
}

// ---------------------------------------------------------------------------
// Pass 2: per-row scale / zero-point.
// ---------------------------------------------------------------------------
__global__ __launch_bounds__(256) void k_scale_zero(
    const float* __restrict__ pmin, const float* __restrict__ pmax,
    float* __restrict__ scale, float* __restrict__ zero)
{
    int r = blockIdx.x * 256 + threadIdx.x;
    if (r >= N_OUT) return;
    float mn = 0.0f, mx = 0.0f;
#pragma unroll
    for (int i = 0; i < 16; ++i) {
        mn = fminf(mn, pmin[(size_t)r * 16 + i]);
        mx = fmaxf(mx, pmax[(size_t)r * 16 + i]);
    }
    float s = fmaxf((mx - mn) / 15.0f, 1e-8f);
    scale[r] = s;
    zero[r] = rintf(-mn / s);
}

// ---------------------------------------------------------------------------
// Pass 3: fake-quant + cast to bf16.  4 elems/thread, exact grid.
// ---------------------------------------------------------------------------
__global__ __launch_bounds__(256) void k_quant_cast(
    const float* __restrict__ wq, const float* __restrict__ scale,
    const float* __restrict__ zero, unsigned short* __restrict__ wb)
{
    size_t i = ((size_t)blockIdx.x * 256 + threadIdx.x) * 4;
    int r = (int)(i >> 12);
    float s = scale[r], z = zero[r];
    float4 v = *(const float4*)(wq + i);
    float in[4] = {v.x, v.y, v.z, v.w};
    unsigned short h[4];
#pragma unroll
    for (int j = 0; j < 4; ++j) {
        float q = rintf(in[j] / s) + z;
        q = fminf(fmaxf(q, 0.0f), 15.0f);
        h[j] = f2bf((q - z) * s);
    }
    unsigned int lo = (unsigned int)h[0] | ((unsigned int)h[1] << 16);
    unsigned int hi = (unsigned int)h[2] | ((unsigned int)h[3] << 16);
    *(unsigned long long*)(wb + i) = ((unsigned long long)hi << 32) | lo;
}

// ---------------------------------------------------------------------------
// Pass 4: x -> bf16.
// ---------------------------------------------------------------------------
__global__ __launch_bounds__(256) void k_cast_x(
    const float* __restrict__ x, unsigned short* __restrict__ xb)
{
    size_t i = ((size_t)blockIdx.x * 256 + threadIdx.x) * 4;
    float4 v = *(const float4*)(x + i);
    unsigned int lo = (unsigned int)f2bf(v.x) | ((unsigned int)f2bf(v.y) << 16);
    unsigned int hi = (unsigned int)f2bf(v.z) | ((unsigned int)f2bf(v.w) << 16);
    *(unsigned long long*)(xb + i) = ((unsigned long long)hi << 32) | lo;
}

// ---------------------------------------------------------------------------
// Pass 5: C[m,n] = sum_k A[m,k]*W[n,k] + bias[n]
// v2 schedule: 256x256 tile, BK=64, 8 waves, 128 KiB LDS, read-AHEAD register
// pipeline. Per phase: {ds_reads for q+1; lgkmcnt(J) [drains older reads];
// stage slot; vmcnt(V); MFMA(q); barrier}. LDS port works during MFMA windows.
//
// Slot order (per tile t, buffer D=t&1): Q0 stages (t+2).Ah0, Q1 (t+2).Bh0,
// Q2 (t+2).Bh1, Q3 (t+2).Ah1.  Reads: Q0 (t).Bh1, Q1 (t).Ah1, Q2 (t+1).Ah0,
// Q3 (t+1).Bh0 -> every stage lands exactly 2 phases after its region's
// read-issue (lgkmcnt(J)+barrier protects), every read 6 slots after its
// stage (vmcnt(10) steady; drain 8,6,4,2 then 0 over last two tiles).
// Reg buffers: af0/af1 (A halves), bE/bO (B, parity-alternating roles).
// Accumulation order identical to previous kernel -> bit-identical output.
// grid (32, 43) = 1376 = 8*172 (bijective XCD swizzle)
// ---------------------------------------------------------------------------
#define NT (K_IN / 64)   // 64 K-tiles

__global__ __launch_bounds__(512, 2) void k_gemm(
    const unsigned short* __restrict__ A,   // bf16 bits [M_ROWS][K_IN]
    const unsigned short* __restrict__ W,   // bf16 bits [N_OUT][K_IN]
    const float* __restrict__ bias,
    float* __restrict__ C)                  // [M_ROWS][N_OUT]
{
    extern __shared__ char lds[];           // 131072 B

    const int tid  = threadIdx.x;
    const int lane = tid & 63;
    const int w    = tid >> 6;              // wave 0..7
    const int wr   = w >> 2;                // 0..1 (M half within mh-half)
    const int wn   = w & 3;                 // 0..3 (N quarter within nh-half)

    // bijective XCD swizzle: 1376 blocks = 8 XCDs x 172
    const int orig = blockIdx.y * gridDim.x + blockIdx.x;
    const int swz  = (orig & 7) * 172 + (orig >> 3);
    const int bm0  = (swz & 31) << 8;       // M tile (gridDim.x = 32)
    const int bn0  = (swz >> 5) << 8;       // N tile 0..42

    // fragment-read lane geometry (st_16x32 swizzled, same data as before)
    const int lrow = lane & 15, lq = lane >> 4;
    const int colA = (lq * 16) ^ (((lrow >> 3) & 1) << 5);  // swizzled col bytes

    // staging lane geometry: linear LDS dest, pre-swizzled global src
    const int srow = w * 16 + (lane >> 2);                        // 0..127
    const int scol = ((lane & 3) * 8) ^ (((lane >> 5) & 1) * 16); // elems

    const unsigned short* pa = A + (size_t)(bm0 + srow) * K_IN + scol;
    const unsigned short* pw = W + (size_t)(bn0 + srow) * K_IN + scol;
    char* ldsw = lds + w * 1024;            // wave-uniform; HW adds lane*16

    char* abase = lds + (wr * 64 + lrow) * 64 + colA;
    char* bbase = lds + 32768 + (wn * 32 + lrow) * 64 + colA;

// stage one 16 KiB half (2 panels) of tile KT into buffer D
#define STAGE_A(D, KT, H) { \
    const unsigned short* s_ = pa + (size_t)((H) * 128) * K_IN + (KT) * 64; \
    char* l_ = ldsw + (D) * 65536 + (H) * 16384; \
    GLDS16(s_,      l_); \
    GLDS16(s_ + 32, l_ + 8192); }
#define STAGE_B(D, KT, H) { \
    const unsigned short* s_ = pw + (size_t)((H) * 128) * K_IN + (KT) * 64; \
    char* l_ = ldsw + (D) * 65536 + 32768 + (H) * 16384; \
    GLDS16(s_,      l_); \
    GLDS16(s_ + 32, l_ + 8192); }

#define READ_A(AF, D, MH) { \
    _Pragma("unroll") for (int mi = 0; mi < 4; ++mi) { \
        AF[mi][0] = *(const bf16x8*)(abase + (D) * 65536 + (MH) * 16384 + mi * 1024); \
        AF[mi][1] = *(const bf16x8*)(abase + (D) * 65536 + (MH) * 16384 + 8192 + mi * 1024); } }
#define READ_B(B_, D, NH) { \
    _Pragma("unroll") for (int ni = 0; ni < 2; ++ni) { \
        B_[ni][0] = *(const bf16x8*)(bbase + (D) * 65536 + (NH) * 16384 + ni * 1024); \
        B_[ni][1] = *(const bf16x8*)(bbase + (D) * 65536 + (NH) * 16384 + 8192 + ni * 1024); } }

#define MFMA_Q(MH, NH, AF, B_) { \
    __builtin_amdgcn_s_setprio(1); \
    _Pragma("unroll") for (int mi = 0; mi < 4; ++mi) \
    _Pragma("unroll") for (int ni = 0; ni < 2; ++ni) { \
        acc[MH][NH][mi][ni] = __builtin_amdgcn_mfma_f32_16x16x32_bf16( \
            AF[mi][0], B_[ni][0], acc[MH][NH][mi][ni], 0, 0, 0); \
        acc[MH][NH][mi][ni] = __builtin_amdgcn_mfma_f32_16x16x32_bf16( \
            AF[mi][1], B_[ni][1], acc[MH][NH][mi][ni], 0, 0, 0); } \
    __builtin_amdgcn_s_setprio(0); }

    f32x4 acc[2][2][4][2] = {};             // 128 VGPRs
    bf16x8 af0[4][2], af1[4][2], bE[2][2], bO[2][2];

    // prologue: stage tiles 0,1 in slot order [Ah0,Bh0,Bh1,Ah1] per tile.
    STAGE_A(0, 0, 0); STAGE_B(0, 0, 0); STAGE_B(0, 0, 1); STAGE_A(0, 0, 1);
    STAGE_A(1, 1, 0); STAGE_B(1, 1, 0); STAGE_B(1, 1, 1); STAGE_A(1, 1, 1);
    VMW(10);                                // T0.{Ah0,Bh0,Bh1} landed
    __builtin_amdgcn_s_barrier();
    READ_A(af0, 0, 0);                      // T0.Ah0
    READ_B(bE, 0, 0);                       // T0.Bh0
    LKW(0);                                 // drain: first in-loop stage
    __builtin_amdgcn_s_barrier();           // overwrites T0.Ah0 region

// BH0 = buffer holding (t).Bh0 (in use); BH1 = read target (Bh1 then next Bh0)
#define TILE_BODY(T, D, DN, BH0, BH1, STG, RDN, V0, V1, V2, V3, LK2, LK3) { \
    /* Q0 (mh0,nh0) */ \
    READ_B(BH1, D, 1); \
    LKW(4); \
    if (STG) STAGE_A(D, (T) + 2, 0); \
    VMW(V0); \
    MFMA_Q(0, 0, af0, BH0); \
    __builtin_amdgcn_s_barrier(); \
    /* Q1 (mh0,nh1) */ \
    READ_A(af1, D, 1); \
    LKW(8); \
    if (STG) STAGE_B(D, (T) + 2, 0); \
    VMW(V1); \
    MFMA_Q(0, 1, af0, BH1); \
    __builtin_amdgcn_s_barrier(); \
    /* Q2 (mh1,nh1) */ \
    if (RDN) READ_A(af0, DN, 0); \
    LKW(LK2); \
    if (STG) STAGE_B(D, (T) + 2, 1); \
    VMW(V2); \
    MFMA_Q(1, 1, af1, BH1); \
    __builtin_amdgcn_s_barrier(); \
    /* Q3 (mh1,nh0) */ \
    if (RDN) READ_B(BH1, DN, 0); \
    LKW(LK3); \
    if (STG) STAGE_A(D, (T) + 2, 1); \
    VMW(V3); \
    MFMA_Q(1, 0, af1, BH0); \
    __builtin_amdgcn_s_barrier(); }

#pragma unroll 1
    for (int tt = 0; tt < NT - 2; tt += 2) {
        TILE_BODY(tt,     0, 1, bE, bO, 1, 1, 10, 10, 10, 10, 8, 4);
        TILE_BODY(tt + 1, 1, 0, bO, bE, 1, 1, 10, 10, 10, 10, 8, 4);
    }
    // tail: tiles 62 (drain vmcnt), 63 (no next-tile reads)
    TILE_BODY(NT - 2, 0, 1, bE, bO, 0, 1, 8, 6, 4, 2, 8, 4);
    TILE_BODY(NT - 1, 1, 0, bO, bE, 0, 0, 0, 0, 0, 0, 0, 0);

    // epilogue: C/D layout col = lane&15, row = (lane>>4)*4 + reg
#pragma unroll
    for (int mh = 0; mh < 2; ++mh)
#pragma unroll
    for (int mi = 0; mi < 4; ++mi) {
        const int row = bm0 + mh * 128 + wr * 64 + mi * 16 + lq * 4;
#pragma unroll
        for (int nh = 0; nh < 2; ++nh)
#pragma unroll
        for (int ni = 0; ni < 2; ++ni) {
            const int col = bn0 + nh * 128 + wn * 32 + ni * 16 + lrow;
            const float bb = bias[col];
            const f32x4 v = acc[mh][nh][mi][ni];
#pragma unroll
            for (int r = 0; r < 4; ++r)
                C[(size_t)(row + r) * N_OUT + col] = v[r] + bb;
        }
    }
}

// ---------------------------------------------------------------------------
extern "C" void kernel_launch(void* const* d_in, const int* in_sizes, int n_in,
                              void* d_out, int out_size, void* d_ws, size_t ws_size,
                              hipStream_t stream)
{
    const float* x      = (const float*)d_in[0];   // [4,2048,4096]
    const float* weight = (const float*)d_in[1];   // [11008,4096]
    const float* Bd     = (const float*)d_in[2];   // [11008,192]
    const float* Bu     = (const float*)d_in[3];   // [192,4096]
    const float* bias   = (const float*)d_in[4];   // [11008]
    float* out = (float*)d_out;                    // [8192,11008] f32

    char* ws = (char*)d_ws;
    float*          wq    = (float*)(ws);                      // 180,355,072 B
    float*          pmin  = (float*)(ws + 180355072);          //     704,512 B
    float*          pmax  = (float*)(ws + 181059584);          //     704,512 B
    float*          scale = (float*)(ws + 181764096);          //      44,032 B
    float*          zero  = (float*)(ws + 181808128);          //      44,032 B
    unsigned short* wb    = (unsigned short*)(ws + 181852160); //  90,177,536 B
    unsigned short* xb    = (unsigned short*)(ws + 272029696); //  67,108,864 B

    static bool attr_set = false;
    if (!attr_set) {
        hipFuncSetAttribute((const void*)k_gemm,
                            hipFuncAttributeMaxDynamicSharedMemorySize, 131072);
        attr_set = true;
    }

    k_delta_minmax<<<dim3(N_OUT / 64, K_IN / 256), 256, 0, stream>>>(
        weight, Bd, Bu, wq, pmin, pmax);
    k_scale_zero<<<(N_OUT + 255) / 256, 256, 0, stream>>>(pmin, pmax, scale, zero);
    k_quant_cast<<<(N_OUT * (K_IN / 4)) / 256, 256, 0, stream>>>(wq, scale, zero, wb);
    k_cast_x<<<(M_ROWS * (K_IN / 4)) / 256, 256, 0, stream>>>(x, xb);
    k_gemm<<<dim3(M_ROWS / 256, N_OUT / 256), 512, 131072, stream>>>(xb, wb, bias, out);
}